// Round 15
// baseline (277.027 us; speedup 1.0000x reference)
//
#include <hip/hip_runtime.h>
#include <hip/hip_bf16.h>

#define NN 50000
#define EE 400000
#define GG 64
#define CAP 48
#define HROW 520   // LDS row stride (bytes) for 512B fp8 rows

typedef unsigned short u16;
typedef unsigned char u8;
typedef long long i64;
typedef unsigned long long u64;
typedef __attribute__((ext_vector_type(8))) short bf16x8;
typedef __attribute__((ext_vector_type(4))) float f32x4;
typedef __attribute__((ext_vector_type(2))) float f32x2;

__device__ __forceinline__ float b2f(u16 u) {
    unsigned int x = ((unsigned int)u) << 16;
    return __uint_as_float(x);
}
__device__ __forceinline__ u16 f2b(float f) {
    unsigned int x = __float_as_uint(f);
    unsigned int r = x + 0x7fffu + ((x >> 16) & 1u);
    return (u16)(r >> 16);
}
// fp8 e4m3 (OCP) via HW converts — internal tensors h1, hL2, W2p only.
__device__ __forceinline__ u8 f2fp8(float f) {
    return (u8)(__builtin_amdgcn_cvt_pk_fp8_f32(f, f, 0, false) & 0xFF);
}
__device__ __forceinline__ f32x2 fp8x2_f32(unsigned int v, bool hi) {
    return hi ? __builtin_amdgcn_cvt_pk_f32_fp8(v, true)
              : __builtin_amdgcn_cvt_pk_f32_fp8(v, false);
}
__device__ __forceinline__ float wred_sum(float v) {
    #pragma unroll
    for (int o = 32; o; o >>= 1) v += __shfl_xor(v, o, 64);
    return v;
}
__device__ __forceinline__ float lrelu(float v) { return v > 0.f ? v : 0.2f * v; }

// ---- fused prep: init CSR + gstart + cvtW2(fp8, K-PERMUTED) + prepW1 + zero pooled.
__global__ void k_prep(const int* __restrict__ batch, int* __restrict__ deg,
                       int* __restrict__ col, int* __restrict__ gstart,
                       const float* __restrict__ W1, const float* __restrict__ as1,
                       const float* __restrict__ ad1, u16* __restrict__ W1p,
                       const float* __restrict__ W2, u8* __restrict__ W2p,
                       float* __restrict__ pooled) {
    __shared__ float asw[16][8];
    int b = blockIdx.x, t = threadIdx.x;
    if (b < 196) {
        int n = b * 256 + t;
        if (n < NN) { deg[n] = 1; col[(size_t)n * CAP] = n; }
    } else if (b == 196) {
        if (t <= GG) {
            int lo = 0, hi = NN;
            while (lo < hi) {
                int mid = (lo + hi) >> 1;
                if (batch[mid] < t) lo = mid + 1; else hi = mid;
            }
            gstart[t] = lo;
        }
    } else if (b < 453) {
        int idx = (b - 197) * 256 + t;   // 65536 total
        int j = idx & 7;
        int l = (idx >> 3) & 63;
        int ct = idx >> 9;
        int c = ct >> 3, tt = ct & 7;
        int p = c * 32 + (l >> 4) * 8 + j;     // K-position
        int lp = p >> 3, jp = p & 7;
        int chan = 128 * (lp >> 4) + 16 * jp + (lp & 15);  // perm(p)
        int n = tt * 16 + (l & 15);
        W2p[idx] = f2fp8(W2[chan * 128 + n]);
    } else if (b == 453) {
        int pair = t >> 1, half = t & 1;
        int k = pair >> 3, h = pair & 7;
        int hd = h & 3;
        const float* att = (h >= 4) ? ad1 : as1;
        float s = 0.f;
        int c0 = half * 64;
        for (int c = c0; c < c0 + 64; c++)
            s += W1[k * 512 + hd * 128 + c] * att[hd * 128 + c];
        s += __shfl_xor(s, 1, 64);
        if (half == 0) asw[k][h] = s;
        __syncthreads();
        for (int idx = t; idx < 33 * 64 * 8; idx += 256) {
            int j = idx & 7, l = (idx >> 3) & 63, tt = idx >> 9;
            int quad = l >> 4, m = l & 15;
            int k2 = quad * 8 + j;
            float v = 0.f;
            if (k2 < 16) {
                if (tt < 32) v = W1[k2 * 512 + tt * 16 + m];
                else if (m < 8) v = asw[k2][m];
            }
            W1p[idx] = f2b(v);
        }
    } else {
        for (int i = t; i < GG * 128; i += 256) pooled[i] = 0.f;
    }
}

// ---- bucket-append edges by dst
__global__ void k_edges(const int* __restrict__ ei, int* __restrict__ deg,
                        int* __restrict__ col) {
    int e = blockIdx.x * 256 + threadIdx.x;
    if (e < EE) {
        int s = ei[e];
        int d = ei[EE + e];
        int slot = atomicAdd(&deg[d], 1);
        if (slot < CAP) col[(size_t)d * CAP + slot] = s;
    }
}

// ---- layer1 linear via MFMA: [h1(fp8,[n][m][tt]) | a_src1 | a_dst1]
__global__ __launch_bounds__(256) void k_gemm1(
    const float* __restrict__ x, const u16* __restrict__ W1p,
    u8* __restrict__ h1, float* __restrict__ a_src1, float* __restrict__ a_dst1) {
    int tid = threadIdx.x;
    int wave = tid >> 6, l = tid & 63;
    int quad = l >> 4, m = l & 15;
    int row0 = blockIdx.x * 64 + wave * 16;
    int arow = row0 + m;
    int arow_c = arow < NN ? arow : (NN - 1);
    bf16x8 af;
    if (quad < 2) {
        const float* xp = x + arow_c * 16 + quad * 8;
        float4 x0 = *(const float4*)(xp);
        float4 x1 = *(const float4*)(xp + 4);
        u16 tmp[8] = {f2b(x0.x), f2b(x0.y), f2b(x0.z), f2b(x0.w),
                      f2b(x1.x), f2b(x1.y), f2b(x1.z), f2b(x1.w)};
        af = *(bf16x8*)tmp;
    } else {
        af = (bf16x8){0, 0, 0, 0, 0, 0, 0, 0};
    }
    const u16* bp = W1p + l * 8;
    f32x4 acc[33];
    #pragma unroll
    for (int tt = 0; tt < 33; tt++) acc[tt] = (f32x4){0.f, 0.f, 0.f, 0.f};
    #pragma unroll
    for (int tt = 0; tt < 33; tt++) {
        bf16x8 bf = *(const bf16x8*)(bp + (size_t)tt * 512);
        acc[tt] = __builtin_amdgcn_mfma_f32_16x16x32_bf16(af, bf, acc[tt], 0, 0, 0);
    }
    #pragma unroll
    for (int r = 0; r < 4; r++) {
        int row = row0 + quad * 4 + r;
        if (row >= NN) continue;
        unsigned int d[8];
        #pragma unroll
        for (int dd = 0; dd < 8; dd++) {
            unsigned int w = __builtin_amdgcn_cvt_pk_fp8_f32(acc[4 * dd][r], acc[4 * dd + 1][r], 0, false);
            w = __builtin_amdgcn_cvt_pk_fp8_f32(acc[4 * dd + 2][r], acc[4 * dd + 3][r], w, true);
            d[dd] = w;
        }
        uint4 v0; v0.x = d[0]; v0.y = d[1]; v0.z = d[2]; v0.w = d[3];
        uint4 v1; v1.x = d[4]; v1.y = d[5]; v1.z = d[6]; v1.w = d[7];
        *(uint4*)(h1 + (size_t)row * 512 + m * 32) = v0;
        *(uint4*)(h1 + (size_t)row * 512 + m * 32 + 16) = v1;
        float v = acc[32][r];
        if (m < 4) a_src1[row * 4 + m] = v;
        else if (m < 8) a_dst1[row * 4 + (m - 4)] = v;
    }
}

// ---- FUSED layer1-aggregation + layer2-linear. Block = 16 nodes, 16 WAVES
// (1024 thr): phase 1 is node-per-wave (restores r13 agg1's 50k-wave
// parallelism), 8 edges/iter. Phase 2: waves 0-7 own one 16-col tile each of
// the 16x128 fp8 GEMM (A from LDS); waves 8-15 idle through barriers.
__global__ __launch_bounds__(1024) void k_mid(
    const int* __restrict__ deg, const int* __restrict__ col,
    const float* __restrict__ a_src1, const float* __restrict__ a_dst1,
    const u8* __restrict__ h1, const float* __restrict__ b1,
    const u8* __restrict__ W2p, const float* __restrict__ as2,
    const float* __restrict__ ad2, u8* __restrict__ hL2,
    float* __restrict__ a_src2, float* __restrict__ a_dst2) {
    __shared__ u64 hrowq[16 * HROW / 8];
    __shared__ float alphaS[16][64][4];
    __shared__ float part[16][2][8];
    u8* hrow = (u8*)hrowq;
    int t = threadIdx.x;
    int w = t >> 6, l = t & 63;
    int n0 = blockIdx.x * 16;
    int g = l >> 4, m = l & 15;
    // ---- phase 1: node n0+w per wave
    {
        int n = n0 + w;
        int dg = min(deg[n], CAP);
        int sl = (l < dg) ? col[(size_t)n * CAP + l] : 0;
        float4 ad = *(const float4*)(a_dst1 + n * 4);
        float4 as = *(const float4*)(a_src1 + (size_t)sl * 4);
        float4 e;
        e.x = __expf(lrelu(as.x + ad.x)); e.y = __expf(lrelu(as.y + ad.y));
        e.z = __expf(lrelu(as.z + ad.z)); e.w = __expf(lrelu(as.w + ad.w));
        if (l >= dg) e = (float4){0.f, 0.f, 0.f, 0.f};
        float4 inv;
        inv.x = 1.0f / wred_sum(e.x);
        inv.y = 1.0f / wred_sum(e.y);
        inv.z = 1.0f / wred_sum(e.z);
        inv.w = 1.0f / wred_sum(e.w);
        {
            float4 a4;
            a4.x = e.x * inv.x; a4.y = e.y * inv.y;
            a4.z = e.z * inv.z; a4.w = e.w * inv.w;
            *(float4*)&alphaS[w][l][0] = a4;   // zeros beyond dg
        }
        const u8* hb = h1 + m * 32 + g * 8;
        f32x2 acc[4] = {{0.f, 0.f}, {0.f, 0.f}, {0.f, 0.f}, {0.f, 0.f}};
        int iters = (dg + 7) >> 3;
        for (int j = 0; j < iters; j++) {
            #pragma unroll
            for (int q = 0; q < 8; q += 2) {
                int eA = 8 * j + q, eB = 8 * j + q + 1;
                int sA = __shfl(sl, eA);
                int sB = __shfl(sl, eB);
                float aA = alphaS[w][eA][g];
                float aB = alphaS[w][eB][g];
                uint2 uA = *(const uint2*)(hb + (size_t)sA * 512);
                uint2 uB = *(const uint2*)(hb + (size_t)sB * 512);
                acc[0] += aA * fp8x2_f32(uA.x, false);
                acc[1] += aA * fp8x2_f32(uA.x, true);
                acc[2] += aA * fp8x2_f32(uA.y, false);
                acc[3] += aA * fp8x2_f32(uA.y, true);
                acc[0] += aB * fp8x2_f32(uB.x, false);
                acc[1] += aB * fp8x2_f32(uB.x, true);
                acc[2] += aB * fp8x2_f32(uB.y, false);
                acc[3] += aB * fp8x2_f32(uB.y, true);
            }
        }
        // channels c_j = 128g + 16j + m; pack into LDS position space
        float av[8] = {acc[0].x, acc[0].y, acc[1].x, acc[1].y,
                       acc[2].x, acc[2].y, acc[3].x, acc[3].y};
        const float* bb = b1 + 128 * g + m;
        float v[8];
        #pragma unroll
        for (int j = 0; j < 8; j++) {
            float q = av[j] + bb[16 * j];
            v[j] = q > 0.f ? q : __expf(q) - 1.0f;
        }
        unsigned int d0 = __builtin_amdgcn_cvt_pk_fp8_f32(v[0], v[1], 0, false);
        d0 = __builtin_amdgcn_cvt_pk_fp8_f32(v[2], v[3], d0, true);
        unsigned int d1 = __builtin_amdgcn_cvt_pk_fp8_f32(v[4], v[5], 0, false);
        d1 = __builtin_amdgcn_cvt_pk_fp8_f32(v[6], v[7], d1, true);
        uint2 ov; ov.x = d0; ov.y = d1;
        *(uint2*)(hrow + w * HROW + l * 8) = ov;
    }
    __syncthreads();
    // ---- phase 2: waves 0-7, col-tile tt=w, A from LDS
    if (w < 8) {
        int quad = l >> 4;
        int tt = w;
        const u8* bbase = W2p + l * 8;
        f32x4 acc2 = (f32x4){0.f, 0.f, 0.f, 0.f};
        #pragma unroll
        for (int c = 0; c < 16; c++) {
            i64 af = *(const i64*)(hrow + m * HROW + c * 32 + quad * 8);
            i64 bf = *(const i64*)(bbase + (size_t)(c * 8 + tt) * 512);
            acc2 = __builtin_amdgcn_mfma_f32_16x16x32_fp8_fp8(af, bf, acc2, 0, 0, 0);
        }
        float asv = as2[tt * 16 + m], adv = ad2[tt * 16 + m];
        #pragma unroll
        for (int r = 0; r < 4; r++) {
            int node = n0 + quad * 4 + r;
            float v = acc2[r];
            hL2[(size_t)node * 128 + tt * 16 + m] = f2fp8(v);
            float rs = v * asv;
            float rd = v * adv;
            #pragma unroll
            for (int o = 1; o < 16; o <<= 1) {
                rs += __shfl_xor(rs, o, 64);
                rd += __shfl_xor(rd, o, 64);
            }
            if (m == 0) { part[quad * 4 + r][0][w] = rs; part[quad * 4 + r][1][w] = rd; }
        }
    }
    __syncthreads();
    if (t < 32) {
        int row = t >> 1, which = t & 1;
        float s = 0.f;
        #pragma unroll
        for (int i = 0; i < 8; i++) s += part[row][which][i];
        if (which) a_dst2[n0 + row] = s; else a_src2[n0 + row] = s;
    }
}

// ---- layer2 attention + aggregation + POOL: WAVE-PER-NODE, fused softmax,
// hL2 channel-major: lane l owns channels 2l, 2l+1.
__global__ __launch_bounds__(256) void k_agg2(
    const int* __restrict__ deg, const int* __restrict__ col,
    const float* __restrict__ a_src2, const float* __restrict__ a_dst2,
    const u8* __restrict__ hL2, const float* __restrict__ b2v,
    const int* __restrict__ batch, float* __restrict__ pooled) {
    __shared__ float red[4][128];
    __shared__ int gS[4];
    int t = threadIdx.x;
    int wave = t >> 6, l = t & 63;
    int n = blockIdx.x * 4 + wave;
    if (n >= NN) return;
    int dg = min(deg[n], CAP);
    int sl = (l < dg) ? col[(size_t)n * CAP + l] : 0;
    float ad = a_dst2[n];
    float e = (l < dg) ? __expf(lrelu(a_src2[sl] + ad)) : 0.f;
    float inv = 1.0f / wred_sum(e);
    float al = e * inv;
    f32x2 acc = {0.f, 0.f};
    const u8* hb = hL2 + l * 2;
    int iters = (dg + 3) >> 2;
    for (int j = 0; j < iters; j++) {
        int e0 = 4 * j, e1 = 4 * j + 1, e2 = 4 * j + 2, e3 = 4 * j + 3;
        int s0 = __shfl(sl, e0), s1 = __shfl(sl, e1);
        int s2 = __shfl(sl, e2), s3 = __shfl(sl, e3);
        float a0 = __shfl(al, e0), a1 = __shfl(al, e1);
        float a2 = __shfl(al, e2), a3 = __shfl(al, e3);
        unsigned int u0 = *(const u16*)(hb + (size_t)s0 * 128);
        unsigned int u1 = *(const u16*)(hb + (size_t)s1 * 128);
        unsigned int u2 = *(const u16*)(hb + (size_t)s2 * 128);
        unsigned int u3 = *(const u16*)(hb + (size_t)s3 * 128);
        acc += a0 * fp8x2_f32(u0, false);
        acc += a1 * fp8x2_f32(u1, false);
        acc += a2 * fp8x2_f32(u2, false);
        acc += a3 * fp8x2_f32(u3, false);
    }
    float o0 = acc.x + b2v[2 * l];     o0 = o0 > 0.f ? o0 : __expf(o0) - 1.0f;
    float o1 = acc.y + b2v[2 * l + 1]; o1 = o1 > 0.f ? o1 : __expf(o1) - 1.0f;
    red[wave][2 * l] = o0;
    red[wave][2 * l + 1] = o1;
    if (l == 0) gS[wave] = batch[n];
    __syncthreads();
    if (t < 128) {
        int g0 = gS[0];
        if (gS[1] == g0 && gS[2] == g0 && gS[3] == g0) {
            float s = red[0][t] + red[1][t] + red[2][t] + red[3][t];
            atomicAdd(&pooled[g0 * 128 + t], s);
        } else {
            #pragma unroll
            for (int w = 0; w < 4; w++)
                atomicAdd(&pooled[gS[w] * 128 + t], red[w][t]);
        }
    }
}

// ---- graph MLP + classifier (pooled holds per-graph SUMS)
__global__ __launch_bounds__(128) void k_head(
    const int* __restrict__ gstart, const float* __restrict__ pooled,
    const float* __restrict__ gfeat,
    const float* __restrict__ Wg1, const float* __restrict__ bg1,
    const float* __restrict__ Wg2, const float* __restrict__ bg2,
    const float* __restrict__ Wc1, const float* __restrict__ bc1,
    const float* __restrict__ Wc2, const float* __restrict__ bc2,
    float* __restrict__ out) {
    __shared__ float z[160];
    __shared__ float hg[32];
    __shared__ float c1b[128];
    int g = blockIdx.x, t = threadIdx.x;
    float cntf = (float)(gstart[g + 1] - gstart[g]);
    z[t] = pooled[g * 128 + t] / fmaxf(cntf, 1.0f);
    if (t < 32) {
        float a = bg1[t];
        for (int i = 0; i < 10; i++) a += gfeat[g * 10 + i] * Wg1[i * 32 + t];
        hg[t] = fmaxf(a, 0.f);
    }
    __syncthreads();
    if (t < 32) {
        float a = bg2[t];
        for (int i = 0; i < 32; i++) a += hg[i] * Wg2[i * 32 + t];
        z[128 + t] = a;
    }
    __syncthreads();
    float a = bc1[t];
    for (int i = 0; i < 160; i++) a += z[i] * Wc1[i * 128 + t];
    c1b[t] = fmaxf(a, 0.f);
    __syncthreads();
    if (t < 6) {
        float o = bc2[t];
        for (int i = 0; i < 128; i++) o += c1b[i] * Wc2[i * 6 + t];
        out[g * 6 + t] = o;
    }
}

extern "C" void kernel_launch(void* const* d_in, const int* in_sizes, int n_in,
                              void* d_out, int out_size, void* d_ws, size_t ws_size,
                              hipStream_t stream) {
    const float* x     = (const float*)d_in[0];
    const int*   ei    = (const int*)d_in[1];
    const int*   batch = (const int*)d_in[2];
    const float* gfeat = (const float*)d_in[3];
    const float* W1    = (const float*)d_in[4];
    const float* as1   = (const float*)d_in[5];
    const float* ad1   = (const float*)d_in[6];
    const float* b1    = (const float*)d_in[7];
    const float* W2    = (const float*)d_in[8];
    const float* as2   = (const float*)d_in[9];
    const float* ad2   = (const float*)d_in[10];
    const float* b2    = (const float*)d_in[11];
    const float* Wg1   = (const float*)d_in[12];
    const float* bg1   = (const float*)d_in[13];
    const float* Wg2   = (const float*)d_in[14];
    const float* bg2   = (const float*)d_in[15];
    const float* Wc1   = (const float*)d_in[16];
    const float* bc1   = (const float*)d_in[17];
    const float* Wc2   = (const float*)d_in[18];
    const float* bc2   = (const float*)d_in[19];
    float* out = (float*)d_out;

    size_t off = 0;
    char* base = (char*)d_ws;
    auto take = [&](size_t nbytes) -> char* {
        char* p = base + off;
        off = (off + nbytes + 255) & ~(size_t)255;
        return p;
    };
    u8*    h1     = (u8*)take((size_t)NN * 512);
    u8*    hL2    = (u8*)take((size_t)NN * 128);
    float* a_src1 = (float*)take((size_t)NN * 4 * 4);
    float* a_dst1 = (float*)take((size_t)NN * 4 * 4);
    float* a_src2 = (float*)take((size_t)NN * 4);
    float* a_dst2 = (float*)take((size_t)NN * 4);
    int*   deg    = (int*)take((size_t)NN * 4);
    int*   col    = (int*)take((size_t)NN * CAP * 4);
    float* pooled = (float*)take(GG * 128 * 4);
    int*   gstart = (int*)take((GG + 1) * 4);
    u8*    W2p    = (u8*)take((size_t)512 * 128);
    u16*   W1p    = (u16*)take((size_t)33 * 64 * 8 * 2);
    (void)ws_size; (void)in_sizes; (void)n_in; (void)out_size;

    k_prep<<<455, 256, 0, stream>>>(batch, deg, col, gstart, W1, as1, ad1, W1p,
                                    W2, W2p, pooled);
    k_edges<<<(EE + 255) / 256, 256, 0, stream>>>(ei, deg, col);
    k_gemm1<<<(NN + 63) / 64, 256, 0, stream>>>(x, W1p, h1, a_src1, a_dst1);
    k_mid<<<NN / 16, 1024, 0, stream>>>(deg, col, a_src1, a_dst1, h1, b1,
                                        W2p, as2, ad2, hL2, a_src2, a_dst2);
    k_agg2<<<(NN + 3) / 4, 256, 0, stream>>>(deg, col, a_src2, a_dst2, hL2, b2,
                                             batch, pooled);
    k_head<<<GG, 128, 0, stream>>>(gstart, pooled, gfeat, Wg1, bg1, Wg2, bg2,
                                   Wc1, bc1, Wc2, bc2, out);
}

// Round 16
// 250.171 us; speedup vs baseline: 1.1074x; 1.1074x over previous
//
#include <hip/hip_runtime.h>
#include <hip/hip_bf16.h>

#define NN 50000
#define EE 400000
#define GG 64
#define CAP 48
#define HROW 520   // LDS row stride (bytes) for 512B fp8 rows

typedef unsigned short u16;
typedef unsigned char u8;
typedef long long i64;
typedef unsigned long long u64;
typedef __attribute__((ext_vector_type(8))) short bf16x8;
typedef __attribute__((ext_vector_type(4))) float f32x4;
typedef __attribute__((ext_vector_type(2))) float f32x2;

__device__ __forceinline__ float b2f(u16 u) {
    unsigned int x = ((unsigned int)u) << 16;
    return __uint_as_float(x);
}
__device__ __forceinline__ u16 f2b(float f) {
    unsigned int x = __float_as_uint(f);
    unsigned int r = x + 0x7fffu + ((x >> 16) & 1u);
    return (u16)(r >> 16);
}
// fp8 e4m3 (OCP) via HW converts — internal tensors h1, hL2, W2p only.
__device__ __forceinline__ u8 f2fp8(float f) {
    return (u8)(__builtin_amdgcn_cvt_pk_fp8_f32(f, f, 0, false) & 0xFF);
}
__device__ __forceinline__ f32x2 fp8x2_f32(unsigned int v, bool hi) {
    return hi ? __builtin_amdgcn_cvt_pk_f32_fp8(v, true)
              : __builtin_amdgcn_cvt_pk_f32_fp8(v, false);
}
__device__ __forceinline__ float wred_sum(float v) {
    #pragma unroll
    for (int o = 32; o; o >>= 1) v += __shfl_xor(v, o, 64);
    return v;
}
__device__ __forceinline__ float lrelu(float v) { return v > 0.f ? v : 0.2f * v; }

// ---- fused prep + edge-bucketing. deg pre-zeroed by memset; self-loop and
// edge appends are BOTH atomic -> order-independent across blocks.
// grid 2018: [0,1563) edges, [1563,1759) self-loops, 1759 gstart,
// [1760,2016) cvtW2 (K-permuted), 2016 prepW1, 2017 zero pooled.
__global__ void k_pe(const int* __restrict__ ei, const int* __restrict__ batch,
                     int* __restrict__ deg, int* __restrict__ col,
                     int* __restrict__ gstart,
                     const float* __restrict__ W1, const float* __restrict__ as1,
                     const float* __restrict__ ad1, u16* __restrict__ W1p,
                     const float* __restrict__ W2, u8* __restrict__ W2p,
                     float* __restrict__ pooled) {
    __shared__ float asw[16][8];
    int b = blockIdx.x, t = threadIdx.x;
    if (b < 1563) {
        int e = b * 256 + t;
        if (e < EE) {
            int s = ei[e];
            int d = ei[EE + e];
            int slot = atomicAdd(&deg[d], 1);
            if (slot < CAP) col[(size_t)d * CAP + slot] = s;
        }
    } else if (b < 1759) {
        int n = (b - 1563) * 256 + t;
        if (n < NN) {
            int slot = atomicAdd(&deg[n], 1);
            if (slot < CAP) col[(size_t)n * CAP + slot] = n;
        }
    } else if (b == 1759) {
        if (t <= GG) {
            int lo = 0, hi = NN;
            while (lo < hi) {
                int mid = (lo + hi) >> 1;
                if (batch[mid] < t) lo = mid + 1; else hi = mid;
            }
            gstart[t] = lo;
        }
    } else if (b < 2016) {
        int idx = (b - 1760) * 256 + t;   // 65536 total
        int j = idx & 7;
        int l = (idx >> 3) & 63;
        int ct = idx >> 9;
        int c = ct >> 3, tt = ct & 7;
        int p = c * 32 + (l >> 4) * 8 + j;     // K-position
        int lp = p >> 3, jp = p & 7;
        int chan = 128 * (lp >> 4) + 16 * jp + (lp & 15);  // perm(p)
        int n = tt * 16 + (l & 15);
        W2p[idx] = f2fp8(W2[chan * 128 + n]);
    } else if (b == 2016) {
        int pair = t >> 1, half = t & 1;
        int k = pair >> 3, h = pair & 7;
        int hd = h & 3;
        const float* att = (h >= 4) ? ad1 : as1;
        float s = 0.f;
        int c0 = half * 64;
        for (int c = c0; c < c0 + 64; c++)
            s += W1[k * 512 + hd * 128 + c] * att[hd * 128 + c];
        s += __shfl_xor(s, 1, 64);
        if (half == 0) asw[k][h] = s;
        __syncthreads();
        for (int idx = t; idx < 33 * 64 * 8; idx += 256) {
            int j = idx & 7, l = (idx >> 3) & 63, tt = idx >> 9;
            int quad = l >> 4, m = l & 15;
            int k2 = quad * 8 + j;
            float v = 0.f;
            if (k2 < 16) {
                if (tt < 32) v = W1[k2 * 512 + tt * 16 + m];
                else if (m < 8) v = asw[k2][m];
            }
            W1p[idx] = f2b(v);
        }
    } else {
        for (int i = t; i < GG * 128; i += 256) pooled[i] = 0.f;
    }
}

// ---- layer1 linear via MFMA: [h1(fp8,[n][m][tt]) | a_src1 | a_dst1]
__global__ __launch_bounds__(256) void k_gemm1(
    const float* __restrict__ x, const u16* __restrict__ W1p,
    u8* __restrict__ h1, float* __restrict__ a_src1, float* __restrict__ a_dst1) {
    int tid = threadIdx.x;
    int wave = tid >> 6, l = tid & 63;
    int quad = l >> 4, m = l & 15;
    int row0 = blockIdx.x * 64 + wave * 16;
    int arow = row0 + m;
    int arow_c = arow < NN ? arow : (NN - 1);
    bf16x8 af;
    if (quad < 2) {
        const float* xp = x + arow_c * 16 + quad * 8;
        float4 x0 = *(const float4*)(xp);
        float4 x1 = *(const float4*)(xp + 4);
        u16 tmp[8] = {f2b(x0.x), f2b(x0.y), f2b(x0.z), f2b(x0.w),
                      f2b(x1.x), f2b(x1.y), f2b(x1.z), f2b(x1.w)};
        af = *(bf16x8*)tmp;
    } else {
        af = (bf16x8){0, 0, 0, 0, 0, 0, 0, 0};
    }
    const u16* bp = W1p + l * 8;
    f32x4 acc[33];
    #pragma unroll
    for (int tt = 0; tt < 33; tt++) acc[tt] = (f32x4){0.f, 0.f, 0.f, 0.f};
    #pragma unroll
    for (int tt = 0; tt < 33; tt++) {
        bf16x8 bf = *(const bf16x8*)(bp + (size_t)tt * 512);
        acc[tt] = __builtin_amdgcn_mfma_f32_16x16x32_bf16(af, bf, acc[tt], 0, 0, 0);
    }
    #pragma unroll
    for (int r = 0; r < 4; r++) {
        int row = row0 + quad * 4 + r;
        if (row >= NN) continue;
        unsigned int d[8];
        #pragma unroll
        for (int dd = 0; dd < 8; dd++) {
            unsigned int w = __builtin_amdgcn_cvt_pk_fp8_f32(acc[4 * dd][r], acc[4 * dd + 1][r], 0, false);
            w = __builtin_amdgcn_cvt_pk_fp8_f32(acc[4 * dd + 2][r], acc[4 * dd + 3][r], w, true);
            d[dd] = w;
        }
        uint4 v0; v0.x = d[0]; v0.y = d[1]; v0.z = d[2]; v0.w = d[3];
        uint4 v1; v1.x = d[4]; v1.y = d[5]; v1.z = d[6]; v1.w = d[7];
        *(uint4*)(h1 + (size_t)row * 512 + m * 32) = v0;
        *(uint4*)(h1 + (size_t)row * 512 + m * 32 + 16) = v1;
        float v = acc[32][r];
        if (m < 4) a_src1[row * 4 + m] = v;
        else if (m < 8) a_dst1[row * 4 + (m - 4)] = v;
    }
}

// ---- FUSED layer1-aggregation + layer2-linear (r14 structure: 256 thr,
// 4 waves, 16 nodes, 4 serial nodes/wave) with 8-edges/iter gather.
__global__ __launch_bounds__(256) void k_mid(
    const int* __restrict__ deg, const int* __restrict__ col,
    const float* __restrict__ a_src1, const float* __restrict__ a_dst1,
    const u8* __restrict__ h1, const float* __restrict__ b1,
    const u8* __restrict__ W2p, const float* __restrict__ as2,
    const float* __restrict__ ad2, u8* __restrict__ hL2,
    float* __restrict__ a_src2, float* __restrict__ a_dst2) {
    __shared__ u64 hrowq[16 * HROW / 8];
    __shared__ float alphaS[4][64][4];
    __shared__ float part[16][2][4];
    u8* hrow = (u8*)hrowq;
    int t = threadIdx.x;
    int w = t >> 6, l = t & 63;
    int n0 = blockIdx.x * 16;
    int g = l >> 4, m = l & 15;
    const u8* hb = h1 + m * 32 + g * 8;
    // ---- phase 1: aggregation for 4 nodes per wave, 8 edges/iter
    for (int i = 0; i < 4; i++) {
        int n = n0 + w * 4 + i;
        int dg = min(deg[n], CAP);
        int sl = (l < dg) ? col[(size_t)n * CAP + l] : 0;
        float4 ad = *(const float4*)(a_dst1 + n * 4);
        float4 as = *(const float4*)(a_src1 + (size_t)sl * 4);
        float4 e;
        e.x = __expf(lrelu(as.x + ad.x)); e.y = __expf(lrelu(as.y + ad.y));
        e.z = __expf(lrelu(as.z + ad.z)); e.w = __expf(lrelu(as.w + ad.w));
        if (l >= dg) e = (float4){0.f, 0.f, 0.f, 0.f};
        float4 inv;
        inv.x = 1.0f / wred_sum(e.x);
        inv.y = 1.0f / wred_sum(e.y);
        inv.z = 1.0f / wred_sum(e.z);
        inv.w = 1.0f / wred_sum(e.w);
        {
            float4 a4;
            a4.x = e.x * inv.x; a4.y = e.y * inv.y;
            a4.z = e.z * inv.z; a4.w = e.w * inv.w;
            *(float4*)&alphaS[w][l][0] = a4;   // zeros beyond dg
        }
        f32x2 acc[4] = {{0.f, 0.f}, {0.f, 0.f}, {0.f, 0.f}, {0.f, 0.f}};
        int iters = (dg + 7) >> 3;
        for (int j = 0; j < iters; j++) {
            #pragma unroll
            for (int q = 0; q < 8; q += 2) {
                int eA = 8 * j + q, eB = 8 * j + q + 1;
                int sA = __shfl(sl, eA);
                int sB = __shfl(sl, eB);
                float aA = alphaS[w][eA][g];
                float aB = alphaS[w][eB][g];
                uint2 uA = *(const uint2*)(hb + (size_t)sA * 512);
                uint2 uB = *(const uint2*)(hb + (size_t)sB * 512);
                acc[0] += aA * fp8x2_f32(uA.x, false);
                acc[1] += aA * fp8x2_f32(uA.x, true);
                acc[2] += aA * fp8x2_f32(uA.y, false);
                acc[3] += aA * fp8x2_f32(uA.y, true);
                acc[0] += aB * fp8x2_f32(uB.x, false);
                acc[1] += aB * fp8x2_f32(uB.x, true);
                acc[2] += aB * fp8x2_f32(uB.y, false);
                acc[3] += aB * fp8x2_f32(uB.y, true);
            }
        }
        // channels c_j = 128g + 16j + m; pack and park in LDS position space
        float av[8] = {acc[0].x, acc[0].y, acc[1].x, acc[1].y,
                       acc[2].x, acc[2].y, acc[3].x, acc[3].y};
        const float* bb = b1 + 128 * g + m;
        float v[8];
        #pragma unroll
        for (int j = 0; j < 8; j++) {
            float q = av[j] + bb[16 * j];
            v[j] = q > 0.f ? q : __expf(q) - 1.0f;
        }
        unsigned int d0 = __builtin_amdgcn_cvt_pk_fp8_f32(v[0], v[1], 0, false);
        d0 = __builtin_amdgcn_cvt_pk_fp8_f32(v[2], v[3], d0, true);
        unsigned int d1 = __builtin_amdgcn_cvt_pk_fp8_f32(v[4], v[5], 0, false);
        d1 = __builtin_amdgcn_cvt_pk_fp8_f32(v[6], v[7], d1, true);
        uint2 ov; ov.x = d0; ov.y = d1;
        *(uint2*)(hrow + (w * 4 + i) * HROW + l * 8) = ov;
    }
    __syncthreads();
    // ---- phase 2: 16x128 fp8 GEMM, A from LDS, wave owns col-tiles 2w,2w+1
    int quad = l >> 4;
    int tt0 = 2 * w;
    const u8* bbase = W2p + l * 8;
    f32x4 accA = (f32x4){0.f, 0.f, 0.f, 0.f};
    f32x4 accB = (f32x4){0.f, 0.f, 0.f, 0.f};
    #pragma unroll
    for (int c = 0; c < 16; c++) {
        i64 af = *(const i64*)(hrow + m * HROW + c * 32 + quad * 8);
        i64 bf0 = *(const i64*)(bbase + (size_t)(c * 8 + tt0) * 512);
        i64 bf1 = *(const i64*)(bbase + (size_t)(c * 8 + tt0 + 1) * 512);
        accA = __builtin_amdgcn_mfma_f32_16x16x32_fp8_fp8(af, bf0, accA, 0, 0, 0);
        accB = __builtin_amdgcn_mfma_f32_16x16x32_fp8_fp8(af, bf1, accB, 0, 0, 0);
    }
    float as0 = as2[tt0 * 16 + m], ad0 = ad2[tt0 * 16 + m];
    float as1v = as2[(tt0 + 1) * 16 + m], ad1v = ad2[(tt0 + 1) * 16 + m];
    #pragma unroll
    for (int r = 0; r < 4; r++) {
        int node = n0 + quad * 4 + r;
        float v0 = accA[r], v1 = accB[r];
        hL2[(size_t)node * 128 + tt0 * 16 + m] = f2fp8(v0);
        hL2[(size_t)node * 128 + (tt0 + 1) * 16 + m] = f2fp8(v1);
        float rs = v0 * as0 + v1 * as1v;
        float rd = v0 * ad0 + v1 * ad1v;
        #pragma unroll
        for (int o = 1; o < 16; o <<= 1) {
            rs += __shfl_xor(rs, o, 64);
            rd += __shfl_xor(rd, o, 64);
        }
        if (m == 0) { part[quad * 4 + r][0][w] = rs; part[quad * 4 + r][1][w] = rd; }
    }
    __syncthreads();
    if (t < 32) {
        int row = t >> 1, which = t & 1;
        float s = part[row][which][0] + part[row][which][1] +
                  part[row][which][2] + part[row][which][3];
        if (which) a_dst2[n0 + row] = s; else a_src2[n0 + row] = s;
    }
}

// ---- layer2 attention + aggregation + POOL: WAVE-PER-NODE, 8 edges/iter.
__global__ __launch_bounds__(256) void k_agg2(
    const int* __restrict__ deg, const int* __restrict__ col,
    const float* __restrict__ a_src2, const float* __restrict__ a_dst2,
    const u8* __restrict__ hL2, const float* __restrict__ b2v,
    const int* __restrict__ batch, float* __restrict__ pooled) {
    __shared__ float red[4][128];
    __shared__ int gS[4];
    int t = threadIdx.x;
    int wave = t >> 6, l = t & 63;
    int n = blockIdx.x * 4 + wave;
    if (n >= NN) return;
    int dg = min(deg[n], CAP);
    int sl = (l < dg) ? col[(size_t)n * CAP + l] : 0;
    float ad = a_dst2[n];
    float e = (l < dg) ? __expf(lrelu(a_src2[sl] + ad)) : 0.f;
    float inv = 1.0f / wred_sum(e);
    float al = e * inv;                   // 0 beyond dg
    f32x2 acc = {0.f, 0.f};
    const u8* hb = hL2 + l * 2;
    int iters = (dg + 7) >> 3;
    for (int j = 0; j < iters; j++) {
        #pragma unroll
        for (int q = 0; q < 8; q += 4) {
            int e0 = 8 * j + q, e1 = e0 + 1, e2 = e0 + 2, e3 = e0 + 3;
            int s0 = __shfl(sl, e0), s1 = __shfl(sl, e1);
            int s2 = __shfl(sl, e2), s3 = __shfl(sl, e3);
            float a0 = __shfl(al, e0), a1 = __shfl(al, e1);
            float a2 = __shfl(al, e2), a3 = __shfl(al, e3);
            unsigned int u0 = *(const u16*)(hb + (size_t)s0 * 128);
            unsigned int u1 = *(const u16*)(hb + (size_t)s1 * 128);
            unsigned int u2 = *(const u16*)(hb + (size_t)s2 * 128);
            unsigned int u3 = *(const u16*)(hb + (size_t)s3 * 128);
            acc += a0 * fp8x2_f32(u0, false);
            acc += a1 * fp8x2_f32(u1, false);
            acc += a2 * fp8x2_f32(u2, false);
            acc += a3 * fp8x2_f32(u3, false);
        }
    }
    float o0 = acc.x + b2v[2 * l];     o0 = o0 > 0.f ? o0 : __expf(o0) - 1.0f;
    float o1 = acc.y + b2v[2 * l + 1]; o1 = o1 > 0.f ? o1 : __expf(o1) - 1.0f;
    red[wave][2 * l] = o0;
    red[wave][2 * l + 1] = o1;
    if (l == 0) gS[wave] = batch[n];
    __syncthreads();
    if (t < 128) {
        int g0 = gS[0];
        if (gS[1] == g0 && gS[2] == g0 && gS[3] == g0) {
            float s = red[0][t] + red[1][t] + red[2][t] + red[3][t];
            atomicAdd(&pooled[g0 * 128 + t], s);
        } else {
            #pragma unroll
            for (int w = 0; w < 4; w++)
                atomicAdd(&pooled[gS[w] * 128 + t], red[w][t]);
        }
    }
}

// ---- graph MLP + classifier (pooled holds per-graph SUMS)
__global__ __launch_bounds__(128) void k_head(
    const int* __restrict__ gstart, const float* __restrict__ pooled,
    const float* __restrict__ gfeat,
    const float* __restrict__ Wg1, const float* __restrict__ bg1,
    const float* __restrict__ Wg2, const float* __restrict__ bg2,
    const float* __restrict__ Wc1, const float* __restrict__ bc1,
    const float* __restrict__ Wc2, const float* __restrict__ bc2,
    float* __restrict__ out) {
    __shared__ float z[160];
    __shared__ float hg[32];
    __shared__ float c1b[128];
    int g = blockIdx.x, t = threadIdx.x;
    float cntf = (float)(gstart[g + 1] - gstart[g]);
    z[t] = pooled[g * 128 + t] / fmaxf(cntf, 1.0f);
    if (t < 32) {
        float a = bg1[t];
        for (int i = 0; i < 10; i++) a += gfeat[g * 10 + i] * Wg1[i * 32 + t];
        hg[t] = fmaxf(a, 0.f);
    }
    __syncthreads();
    if (t < 32) {
        float a = bg2[t];
        for (int i = 0; i < 32; i++) a += hg[i] * Wg2[i * 32 + t];
        z[128 + t] = a;
    }
    __syncthreads();
    float a = bc1[t];
    for (int i = 0; i < 160; i++) a += z[i] * Wc1[i * 128 + t];
    c1b[t] = fmaxf(a, 0.f);
    __syncthreads();
    if (t < 6) {
        float o = bc2[t];
        for (int i = 0; i < 128; i++) o += c1b[i] * Wc2[i * 6 + t];
        out[g * 6 + t] = o;
    }
}

extern "C" void kernel_launch(void* const* d_in, const int* in_sizes, int n_in,
                              void* d_out, int out_size, void* d_ws, size_t ws_size,
                              hipStream_t stream) {
    const float* x     = (const float*)d_in[0];
    const int*   ei    = (const int*)d_in[1];
    const int*   batch = (const int*)d_in[2];
    const float* gfeat = (const float*)d_in[3];
    const float* W1    = (const float*)d_in[4];
    const float* as1   = (const float*)d_in[5];
    const float* ad1   = (const float*)d_in[6];
    const float* b1    = (const float*)d_in[7];
    const float* W2    = (const float*)d_in[8];
    const float* as2   = (const float*)d_in[9];
    const float* ad2   = (const float*)d_in[10];
    const float* b2    = (const float*)d_in[11];
    const float* Wg1   = (const float*)d_in[12];
    const float* bg1   = (const float*)d_in[13];
    const float* Wg2   = (const float*)d_in[14];
    const float* bg2   = (const float*)d_in[15];
    const float* Wc1   = (const float*)d_in[16];
    const float* bc1   = (const float*)d_in[17];
    const float* Wc2   = (const float*)d_in[18];
    const float* bc2   = (const float*)d_in[19];
    float* out = (float*)d_out;

    size_t off = 0;
    char* base = (char*)d_ws;
    auto take = [&](size_t nbytes) -> char* {
        char* p = base + off;
        off = (off + nbytes + 255) & ~(size_t)255;
        return p;
    };
    u8*    h1     = (u8*)take((size_t)NN * 512);
    u8*    hL2    = (u8*)take((size_t)NN * 128);
    float* a_src1 = (float*)take((size_t)NN * 4 * 4);
    float* a_dst1 = (float*)take((size_t)NN * 4 * 4);
    float* a_src2 = (float*)take((size_t)NN * 4);
    float* a_dst2 = (float*)take((size_t)NN * 4);
    int*   deg    = (int*)take((size_t)NN * 4);
    int*   col    = (int*)take((size_t)NN * CAP * 4);
    float* pooled = (float*)take(GG * 128 * 4);
    int*   gstart = (int*)take((GG + 1) * 4);
    u8*    W2p    = (u8*)take((size_t)512 * 128);
    u16*   W1p    = (u16*)take((size_t)33 * 64 * 8 * 2);
    (void)ws_size; (void)in_sizes; (void)n_in; (void)out_size;

    hipMemsetAsync(deg, 0, (size_t)NN * 4, stream);
    k_pe<<<2018, 256, 0, stream>>>(ei, batch, deg, col, gstart,
                                   W1, as1, ad1, W1p, W2, W2p, pooled);
    k_gemm1<<<(NN + 63) / 64, 256, 0, stream>>>(x, W1p, h1, a_src1, a_dst1);
    k_mid<<<NN / 16, 256, 0, stream>>>(deg, col, a_src1, a_dst1, h1, b1,
                                       W2p, as2, ad2, hL2, a_src2, a_dst2);
    k_agg2<<<(NN + 3) / 4, 256, 0, stream>>>(deg, col, a_src2, a_dst2, hL2, b2,
                                             batch, pooled);
    k_head<<<GG, 128, 0, stream>>>(gstart, pooled, gfeat, Wg1, bg1, Wg2, bg2,
                                   Wc1, bc1, Wc2, bc2, out);
}

// Round 17
// 243.804 us; speedup vs baseline: 1.1363x; 1.0261x over previous
//
#include <hip/hip_runtime.h>
#include <hip/hip_bf16.h>

#define NN 50000
#define EE 400000
#define GG 64
#define CAP 48
#define HROW 520   // LDS row stride (bytes) for 512B fp8 rows

typedef unsigned short u16;
typedef unsigned char u8;
typedef long long i64;
typedef unsigned long long u64;
typedef __attribute__((ext_vector_type(8))) short bf16x8;
typedef __attribute__((ext_vector_type(4))) float f32x4;
typedef __attribute__((ext_vector_type(2))) float f32x2;

__device__ __forceinline__ float b2f(u16 u) {
    unsigned int x = ((unsigned int)u) << 16;
    return __uint_as_float(x);
}
__device__ __forceinline__ u16 f2b(float f) {
    unsigned int x = __float_as_uint(f);
    unsigned int r = x + 0x7fffu + ((x >> 16) & 1u);
    return (u16)(r >> 16);
}
// fp8 e4m3 (OCP) via HW converts — internal tensors h1, hL2, W2p only.
__device__ __forceinline__ u8 f2fp8(float f) {
    return (u8)(__builtin_amdgcn_cvt_pk_fp8_f32(f, f, 0, false) & 0xFF);
}
__device__ __forceinline__ f32x2 fp8x2_f32(unsigned int v, bool hi) {
    return hi ? __builtin_amdgcn_cvt_pk_f32_fp8(v, true)
              : __builtin_amdgcn_cvt_pk_f32_fp8(v, false);
}
__device__ __forceinline__ float wred_sum(float v) {
    #pragma unroll
    for (int o = 32; o; o >>= 1) v += __shfl_xor(v, o, 64);
    return v;
}
__device__ __forceinline__ float lrelu(float v) { return v > 0.f ? v : 0.2f * v; }

// ---- fused prep + edge-bucketing. deg pre-zeroed by memset; self-loop and
// edge appends are BOTH atomic -> order-independent across blocks.
// grid 2018: [0,1563) edges, [1563,1759) self-loops, 1759 gstart,
// [1760,2016) cvtW2 (K-permuted), 2016 prepW1, 2017 zero pooled.
__global__ void k_pe(const int* __restrict__ ei, const int* __restrict__ batch,
                     int* __restrict__ deg, int* __restrict__ col,
                     int* __restrict__ gstart,
                     const float* __restrict__ W1, const float* __restrict__ as1,
                     const float* __restrict__ ad1, u16* __restrict__ W1p,
                     const float* __restrict__ W2, u8* __restrict__ W2p,
                     float* __restrict__ pooled) {
    __shared__ float asw[16][8];
    int b = blockIdx.x, t = threadIdx.x;
    if (b < 1563) {
        int e = b * 256 + t;
        if (e < EE) {
            int s = ei[e];
            int d = ei[EE + e];
            int slot = atomicAdd(&deg[d], 1);
            if (slot < CAP) col[(size_t)d * CAP + slot] = s;
        }
    } else if (b < 1759) {
        int n = (b - 1563) * 256 + t;
        if (n < NN) {
            int slot = atomicAdd(&deg[n], 1);
            if (slot < CAP) col[(size_t)n * CAP + slot] = n;
        }
    } else if (b == 1759) {
        if (t <= GG) {
            int lo = 0, hi = NN;
            while (lo < hi) {
                int mid = (lo + hi) >> 1;
                if (batch[mid] < t) lo = mid + 1; else hi = mid;
            }
            gstart[t] = lo;
        }
    } else if (b < 2016) {
        int idx = (b - 1760) * 256 + t;   // 65536 total
        int j = idx & 7;
        int l = (idx >> 3) & 63;
        int ct = idx >> 9;
        int c = ct >> 3, tt = ct & 7;
        int p = c * 32 + (l >> 4) * 8 + j;     // K-position
        int lp = p >> 3, jp = p & 7;
        int chan = 128 * (lp >> 4) + 16 * jp + (lp & 15);  // perm(p)
        int n = tt * 16 + (l & 15);
        W2p[idx] = f2fp8(W2[chan * 128 + n]);
    } else if (b == 2016) {
        int pair = t >> 1, half = t & 1;
        int k = pair >> 3, h = pair & 7;
        int hd = h & 3;
        const float* att = (h >= 4) ? ad1 : as1;
        float s = 0.f;
        int c0 = half * 64;
        for (int c = c0; c < c0 + 64; c++)
            s += W1[k * 512 + hd * 128 + c] * att[hd * 128 + c];
        s += __shfl_xor(s, 1, 64);
        if (half == 0) asw[k][h] = s;
        __syncthreads();
        for (int idx = t; idx < 33 * 64 * 8; idx += 256) {
            int j = idx & 7, l = (idx >> 3) & 63, tt = idx >> 9;
            int quad = l >> 4, m = l & 15;
            int k2 = quad * 8 + j;
            float v = 0.f;
            if (k2 < 16) {
                if (tt < 32) v = W1[k2 * 512 + tt * 16 + m];
                else if (m < 8) v = asw[k2][m];
            }
            W1p[idx] = f2b(v);
        }
    } else {
        for (int i = t; i < GG * 128; i += 256) pooled[i] = 0.f;
    }
}

// ---- layer1 linear via MFMA: [h1(fp8,[n][m][tt]) | a_src1 | a_dst1]
__global__ __launch_bounds__(256) void k_gemm1(
    const float* __restrict__ x, const u16* __restrict__ W1p,
    u8* __restrict__ h1, float* __restrict__ a_src1, float* __restrict__ a_dst1) {
    int tid = threadIdx.x;
    int wave = tid >> 6, l = tid & 63;
    int quad = l >> 4, m = l & 15;
    int row0 = blockIdx.x * 64 + wave * 16;
    int arow = row0 + m;
    int arow_c = arow < NN ? arow : (NN - 1);
    bf16x8 af;
    if (quad < 2) {
        const float* xp = x + arow_c * 16 + quad * 8;
        float4 x0 = *(const float4*)(xp);
        float4 x1 = *(const float4*)(xp + 4);
        u16 tmp[8] = {f2b(x0.x), f2b(x0.y), f2b(x0.z), f2b(x0.w),
                      f2b(x1.x), f2b(x1.y), f2b(x1.z), f2b(x1.w)};
        af = *(bf16x8*)tmp;
    } else {
        af = (bf16x8){0, 0, 0, 0, 0, 0, 0, 0};
    }
    const u16* bp = W1p + l * 8;
    f32x4 acc[33];
    #pragma unroll
    for (int tt = 0; tt < 33; tt++) acc[tt] = (f32x4){0.f, 0.f, 0.f, 0.f};
    #pragma unroll
    for (int tt = 0; tt < 33; tt++) {
        bf16x8 bf = *(const bf16x8*)(bp + (size_t)tt * 512);
        acc[tt] = __builtin_amdgcn_mfma_f32_16x16x32_bf16(af, bf, acc[tt], 0, 0, 0);
    }
    #pragma unroll
    for (int r = 0; r < 4; r++) {
        int row = row0 + quad * 4 + r;
        if (row >= NN) continue;
        unsigned int d[8];
        #pragma unroll
        for (int dd = 0; dd < 8; dd++) {
            unsigned int w = __builtin_amdgcn_cvt_pk_fp8_f32(acc[4 * dd][r], acc[4 * dd + 1][r], 0, false);
            w = __builtin_amdgcn_cvt_pk_fp8_f32(acc[4 * dd + 2][r], acc[4 * dd + 3][r], w, true);
            d[dd] = w;
        }
        uint4 v0; v0.x = d[0]; v0.y = d[1]; v0.z = d[2]; v0.w = d[3];
        uint4 v1; v1.x = d[4]; v1.y = d[5]; v1.z = d[6]; v1.w = d[7];
        *(uint4*)(h1 + (size_t)row * 512 + m * 32) = v0;
        *(uint4*)(h1 + (size_t)row * 512 + m * 32 + 16) = v1;
        float v = acc[32][r];
        if (m < 4) a_src1[row * 4 + m] = v;
        else if (m < 8) a_dst1[row * 4 + (m - 4)] = v;
    }
}

// ---- FUSED layer1-aggregation + layer2-linear (r14-proven structure:
// 256 thr, 4 waves, 16 nodes, 4 serial nodes/wave, 4 edges/iter).
__global__ __launch_bounds__(256) void k_mid(
    const int* __restrict__ deg, const int* __restrict__ col,
    const float* __restrict__ a_src1, const float* __restrict__ a_dst1,
    const u8* __restrict__ h1, const float* __restrict__ b1,
    const u8* __restrict__ W2p, const float* __restrict__ as2,
    const float* __restrict__ ad2, u8* __restrict__ hL2,
    float* __restrict__ a_src2, float* __restrict__ a_dst2) {
    __shared__ u64 hrowq[16 * HROW / 8];
    __shared__ float alphaS[4][64][4];
    __shared__ float part[16][2][4];
    u8* hrow = (u8*)hrowq;
    int t = threadIdx.x;
    int w = t >> 6, l = t & 63;
    int n0 = blockIdx.x * 16;
    int g = l >> 4, m = l & 15;
    const u8* hb = h1 + m * 32 + g * 8;
    // ---- phase 1: aggregation for 4 nodes per wave
    for (int i = 0; i < 4; i++) {
        int n = n0 + w * 4 + i;
        int dg = min(deg[n], CAP);
        int sl = (l < dg) ? col[(size_t)n * CAP + l] : 0;
        float4 ad = *(const float4*)(a_dst1 + n * 4);
        float4 as = *(const float4*)(a_src1 + (size_t)sl * 4);
        float4 e;
        e.x = __expf(lrelu(as.x + ad.x)); e.y = __expf(lrelu(as.y + ad.y));
        e.z = __expf(lrelu(as.z + ad.z)); e.w = __expf(lrelu(as.w + ad.w));
        if (l >= dg) e = (float4){0.f, 0.f, 0.f, 0.f};
        float4 inv;
        inv.x = 1.0f / wred_sum(e.x);
        inv.y = 1.0f / wred_sum(e.y);
        inv.z = 1.0f / wred_sum(e.z);
        inv.w = 1.0f / wred_sum(e.w);
        {
            float4 a4;
            a4.x = e.x * inv.x; a4.y = e.y * inv.y;
            a4.z = e.z * inv.z; a4.w = e.w * inv.w;
            *(float4*)&alphaS[w][l][0] = a4;   // zeros beyond dg
        }
        f32x2 acc[4] = {{0.f, 0.f}, {0.f, 0.f}, {0.f, 0.f}, {0.f, 0.f}};
        int iters = (dg + 3) >> 2;
        for (int j = 0; j < iters; j++) {
            int e0 = 4 * j, e1 = 4 * j + 1, e2 = 4 * j + 2, e3 = 4 * j + 3;
            int s0 = __shfl(sl, e0), s1 = __shfl(sl, e1);
            int s2 = __shfl(sl, e2), s3 = __shfl(sl, e3);
            float a0 = alphaS[w][e0][g], a1 = alphaS[w][e1][g];
            float a2 = alphaS[w][e2][g], a3 = alphaS[w][e3][g];
            uint2 u0 = *(const uint2*)(hb + (size_t)s0 * 512);
            uint2 u1 = *(const uint2*)(hb + (size_t)s1 * 512);
            uint2 u2 = *(const uint2*)(hb + (size_t)s2 * 512);
            uint2 u3 = *(const uint2*)(hb + (size_t)s3 * 512);
            acc[0] += a0 * fp8x2_f32(u0.x, false);
            acc[1] += a0 * fp8x2_f32(u0.x, true);
            acc[2] += a0 * fp8x2_f32(u0.y, false);
            acc[3] += a0 * fp8x2_f32(u0.y, true);
            acc[0] += a1 * fp8x2_f32(u1.x, false);
            acc[1] += a1 * fp8x2_f32(u1.x, true);
            acc[2] += a1 * fp8x2_f32(u1.y, false);
            acc[3] += a1 * fp8x2_f32(u1.y, true);
            acc[0] += a2 * fp8x2_f32(u2.x, false);
            acc[1] += a2 * fp8x2_f32(u2.x, true);
            acc[2] += a2 * fp8x2_f32(u2.y, false);
            acc[3] += a2 * fp8x2_f32(u2.y, true);
            acc[0] += a3 * fp8x2_f32(u3.x, false);
            acc[1] += a3 * fp8x2_f32(u3.x, true);
            acc[2] += a3 * fp8x2_f32(u3.y, false);
            acc[3] += a3 * fp8x2_f32(u3.y, true);
        }
        // channels c_j = 128g + 16j + m; pack and park in LDS position space
        float av[8] = {acc[0].x, acc[0].y, acc[1].x, acc[1].y,
                       acc[2].x, acc[2].y, acc[3].x, acc[3].y};
        const float* bb = b1 + 128 * g + m;
        float v[8];
        #pragma unroll
        for (int j = 0; j < 8; j++) {
            float q = av[j] + bb[16 * j];
            v[j] = q > 0.f ? q : __expf(q) - 1.0f;
        }
        unsigned int d0 = __builtin_amdgcn_cvt_pk_fp8_f32(v[0], v[1], 0, false);
        d0 = __builtin_amdgcn_cvt_pk_fp8_f32(v[2], v[3], d0, true);
        unsigned int d1 = __builtin_amdgcn_cvt_pk_fp8_f32(v[4], v[5], 0, false);
        d1 = __builtin_amdgcn_cvt_pk_fp8_f32(v[6], v[7], d1, true);
        uint2 ov; ov.x = d0; ov.y = d1;
        *(uint2*)(hrow + (w * 4 + i) * HROW + l * 8) = ov;
    }
    __syncthreads();
    // ---- phase 2: 16x128 fp8 GEMM, A from LDS, wave owns col-tiles 2w,2w+1
    int quad = l >> 4;
    int tt0 = 2 * w;
    const u8* bbase = W2p + l * 8;
    f32x4 accA = (f32x4){0.f, 0.f, 0.f, 0.f};
    f32x4 accB = (f32x4){0.f, 0.f, 0.f, 0.f};
    #pragma unroll
    for (int c = 0; c < 16; c++) {
        i64 af = *(const i64*)(hrow + m * HROW + c * 32 + quad * 8);
        i64 bf0 = *(const i64*)(bbase + (size_t)(c * 8 + tt0) * 512);
        i64 bf1 = *(const i64*)(bbase + (size_t)(c * 8 + tt0 + 1) * 512);
        accA = __builtin_amdgcn_mfma_f32_16x16x32_fp8_fp8(af, bf0, accA, 0, 0, 0);
        accB = __builtin_amdgcn_mfma_f32_16x16x32_fp8_fp8(af, bf1, accB, 0, 0, 0);
    }
    float as0 = as2[tt0 * 16 + m], ad0 = ad2[tt0 * 16 + m];
    float as1v = as2[(tt0 + 1) * 16 + m], ad1v = ad2[(tt0 + 1) * 16 + m];
    #pragma unroll
    for (int r = 0; r < 4; r++) {
        int node = n0 + quad * 4 + r;
        float v0 = accA[r], v1 = accB[r];
        hL2[(size_t)node * 128 + tt0 * 16 + m] = f2fp8(v0);
        hL2[(size_t)node * 128 + (tt0 + 1) * 16 + m] = f2fp8(v1);
        float rs = v0 * as0 + v1 * as1v;
        float rd = v0 * ad0 + v1 * ad1v;
        #pragma unroll
        for (int o = 1; o < 16; o <<= 1) {
            rs += __shfl_xor(rs, o, 64);
            rd += __shfl_xor(rd, o, 64);
        }
        if (m == 0) { part[quad * 4 + r][0][w] = rs; part[quad * 4 + r][1][w] = rd; }
    }
    __syncthreads();
    if (t < 32) {
        int row = t >> 1, which = t & 1;
        float s = part[row][which][0] + part[row][which][1] +
                  part[row][which][2] + part[row][which][3];
        if (which) a_dst2[n0 + row] = s; else a_src2[n0 + row] = s;
    }
}

// ---- layer2 attention + aggregation + POOL: WAVE-PER-NODE, 4 edges/iter.
__global__ __launch_bounds__(256) void k_agg2(
    const int* __restrict__ deg, const int* __restrict__ col,
    const float* __restrict__ a_src2, const float* __restrict__ a_dst2,
    const u8* __restrict__ hL2, const float* __restrict__ b2v,
    const int* __restrict__ batch, float* __restrict__ pooled) {
    __shared__ float red[4][128];
    __shared__ int gS[4];
    int t = threadIdx.x;
    int wave = t >> 6, l = t & 63;
    int n = blockIdx.x * 4 + wave;
    if (n >= NN) return;
    int dg = min(deg[n], CAP);
    int sl = (l < dg) ? col[(size_t)n * CAP + l] : 0;
    float ad = a_dst2[n];
    float e = (l < dg) ? __expf(lrelu(a_src2[sl] + ad)) : 0.f;
    float inv = 1.0f / wred_sum(e);
    float al = e * inv;
    f32x2 acc = {0.f, 0.f};
    const u8* hb = hL2 + l * 2;
    int iters = (dg + 3) >> 2;
    for (int j = 0; j < iters; j++) {
        int e0 = 4 * j, e1 = 4 * j + 1, e2 = 4 * j + 2, e3 = 4 * j + 3;
        int s0 = __shfl(sl, e0), s1 = __shfl(sl, e1);
        int s2 = __shfl(sl, e2), s3 = __shfl(sl, e3);
        float a0 = __shfl(al, e0), a1 = __shfl(al, e1);
        float a2 = __shfl(al, e2), a3 = __shfl(al, e3);
        unsigned int u0 = *(const u16*)(hb + (size_t)s0 * 128);
        unsigned int u1 = *(const u16*)(hb + (size_t)s1 * 128);
        unsigned int u2 = *(const u16*)(hb + (size_t)s2 * 128);
        unsigned int u3 = *(const u16*)(hb + (size_t)s3 * 128);
        acc += a0 * fp8x2_f32(u0, false);
        acc += a1 * fp8x2_f32(u1, false);
        acc += a2 * fp8x2_f32(u2, false);
        acc += a3 * fp8x2_f32(u3, false);
    }
    float o0 = acc.x + b2v[2 * l];     o0 = o0 > 0.f ? o0 : __expf(o0) - 1.0f;
    float o1 = acc.y + b2v[2 * l + 1]; o1 = o1 > 0.f ? o1 : __expf(o1) - 1.0f;
    red[wave][2 * l] = o0;
    red[wave][2 * l + 1] = o1;
    if (l == 0) gS[wave] = batch[n];
    __syncthreads();
    if (t < 128) {
        int g0 = gS[0];
        if (gS[1] == g0 && gS[2] == g0 && gS[3] == g0) {
            float s = red[0][t] + red[1][t] + red[2][t] + red[3][t];
            atomicAdd(&pooled[g0 * 128 + t], s);
        } else {
            #pragma unroll
            for (int w = 0; w < 4; w++)
                atomicAdd(&pooled[gS[w] * 128 + t], red[w][t]);
        }
    }
}

// ---- graph MLP + classifier (pooled holds per-graph SUMS)
__global__ __launch_bounds__(128) void k_head(
    const int* __restrict__ gstart, const float* __restrict__ pooled,
    const float* __restrict__ gfeat,
    const float* __restrict__ Wg1, const float* __restrict__ bg1,
    const float* __restrict__ Wg2, const float* __restrict__ bg2,
    const float* __restrict__ Wc1, const float* __restrict__ bc1,
    const float* __restrict__ Wc2, const float* __restrict__ bc2,
    float* __restrict__ out) {
    __shared__ float z[160];
    __shared__ float hg[32];
    __shared__ float c1b[128];
    int g = blockIdx.x, t = threadIdx.x;
    float cntf = (float)(gstart[g + 1] - gstart[g]);
    z[t] = pooled[g * 128 + t] / fmaxf(cntf, 1.0f);
    if (t < 32) {
        float a = bg1[t];
        for (int i = 0; i < 10; i++) a += gfeat[g * 10 + i] * Wg1[i * 32 + t];
        hg[t] = fmaxf(a, 0.f);
    }
    __syncthreads();
    if (t < 32) {
        float a = bg2[t];
        for (int i = 0; i < 32; i++) a += hg[i] * Wg2[i * 32 + t];
        z[128 + t] = a;
    }
    __syncthreads();
    float a = bc1[t];
    for (int i = 0; i < 160; i++) a += z[i] * Wc1[i * 128 + t];
    c1b[t] = fmaxf(a, 0.f);
    __syncthreads();
    if (t < 6) {
        float o = bc2[t];
        for (int i = 0; i < 128; i++) o += c1b[i] * Wc2[i * 6 + t];
        out[g * 6 + t] = o;
    }
}

extern "C" void kernel_launch(void* const* d_in, const int* in_sizes, int n_in,
                              void* d_out, int out_size, void* d_ws, size_t ws_size,
                              hipStream_t stream) {
    const float* x     = (const float*)d_in[0];
    const int*   ei    = (const int*)d_in[1];
    const int*   batch = (const int*)d_in[2];
    const float* gfeat = (const float*)d_in[3];
    const float* W1    = (const float*)d_in[4];
    const float* as1   = (const float*)d_in[5];
    const float* ad1   = (const float*)d_in[6];
    const float* b1    = (const float*)d_in[7];
    const float* W2    = (const float*)d_in[8];
    const float* as2   = (const float*)d_in[9];
    const float* ad2   = (const float*)d_in[10];
    const float* b2    = (const float*)d_in[11];
    const float* Wg1   = (const float*)d_in[12];
    const float* bg1   = (const float*)d_in[13];
    const float* Wg2   = (const float*)d_in[14];
    const float* bg2   = (const float*)d_in[15];
    const float* Wc1   = (const float*)d_in[16];
    const float* bc1   = (const float*)d_in[17];
    const float* Wc2   = (const float*)d_in[18];
    const float* bc2   = (const float*)d_in[19];
    float* out = (float*)d_out;

    size_t off = 0;
    char* base = (char*)d_ws;
    auto take = [&](size_t nbytes) -> char* {
        char* p = base + off;
        off = (off + nbytes + 255) & ~(size_t)255;
        return p;
    };
    u8*    h1     = (u8*)take((size_t)NN * 512);
    u8*    hL2    = (u8*)take((size_t)NN * 128);
    float* a_src1 = (float*)take((size_t)NN * 4 * 4);
    float* a_dst1 = (float*)take((size_t)NN * 4 * 4);
    float* a_src2 = (float*)take((size_t)NN * 4);
    float* a_dst2 = (float*)take((size_t)NN * 4);
    int*   deg    = (int*)take((size_t)NN * 4);
    int*   col    = (int*)take((size_t)NN * CAP * 4);
    float* pooled = (float*)take(GG * 128 * 4);
    int*   gstart = (int*)take((GG + 1) * 4);
    u8*    W2p    = (u8*)take((size_t)512 * 128);
    u16*   W1p    = (u16*)take((size_t)33 * 64 * 8 * 2);
    (void)ws_size; (void)in_sizes; (void)n_in; (void)out_size;

    hipMemsetAsync(deg, 0, (size_t)NN * 4, stream);
    k_pe<<<2018, 256, 0, stream>>>(ei, batch, deg, col, gstart,
                                   W1, as1, ad1, W1p, W2, W2p, pooled);
    k_gemm1<<<(NN + 63) / 64, 256, 0, stream>>>(x, W1p, h1, a_src1, a_dst1);
    k_mid<<<NN / 16, 256, 0, stream>>>(deg, col, a_src1, a_dst1, h1, b1,
                                       W2p, as2, ad2, hL2, a_src2, a_dst2);
    k_agg2<<<(NN + 3) / 4, 256, 0, stream>>>(deg, col, a_src2, a_dst2, hL2, b2,
                                             batch, pooled);
    k_head<<<GG, 128, 0, stream>>>(gstart, pooled, gfeat, Wg1, bg1, Wg2, bg2,
                                   Wc1, bc1, Wc2, bc2, out);
}